// Round 10
// baseline (699.911 us; speedup 1.0000x reference)
//
#include <hip/hip_runtime.h>
#include <cstdint>
#include <cstddef>

typedef unsigned short ushort;
typedef unsigned int uint;
typedef __attribute__((ext_vector_type(8))) short short8;
typedef __attribute__((ext_vector_type(8))) unsigned short ushort8;
typedef __attribute__((ext_vector_type(4))) unsigned short us4;
typedef __attribute__((ext_vector_type(4))) float float4v;

#define DM    2048
#define INNERC 4096
#define LSEQ  4096
#define NBATCH 2
#define MROWS 8192      // NBATCH*LSEQ
#define NHH   64
#define HDD   64
#define NCHUNK 32
#define CHLEN  128
#define NSCAN  512      // scan blocks: 2 batch * 32 chunk * 8 slice

__device__ __forceinline__ float bf2f(ushort u) {
    return __uint_as_float(((unsigned int)u) << 16);
}
__device__ __forceinline__ ushort f2bf(float f) {
    unsigned int u = __float_as_uint(f);
    unsigned int r = u + 0x7FFFu + ((u >> 16) & 1u);
    return (ushort)(r >> 16);
}

// async global->LDS 16B copy. LDS dest is wave-uniform base + lane*16.
__device__ __forceinline__ void async_cp16(const ushort* __restrict__ g, ushort* l) {
    __builtin_amdgcn_global_load_lds(
        (const __attribute__((address_space(1))) unsigned int*)g,
        (__attribute__((address_space(3))) unsigned int*)l,
        16, 0, 0);
}

// ---------------- diagnostic ----------------
__global__ void diag_kernel(float* __restrict__ out, float val) {
    if (threadIdx.x == 0 && blockIdx.x == 0) out[0] = val;
}

// ---------------- f32 -> bf16 cast (single range) ----------------
__global__ __launch_bounds__(256) void cast_bf16_kernel(
    const float* __restrict__ in, ushort* __restrict__ out, int n) {
    const int i = (blockIdx.x * 256 + threadIdx.x) * 8;
    if (i + 8 > n) return;
    const float4v a = *(const float4v*)(in + i);
    const float4v b = *(const float4v*)(in + i + 4);
    ushort8 o;
    o[0] = f2bf(a[0]); o[1] = f2bf(a[1]); o[2] = f2bf(a[2]); o[3] = f2bf(a[3]);
    o[4] = f2bf(b[0]); o[5] = f2bf(b[1]); o[6] = f2bf(b[2]); o[7] = f2bf(b[3]);
    *(ushort8*)(out + i) = o;
}

// ---------------- f32 -> bf16 cast (two ranges in one launch) ----------------
__global__ __launch_bounds__(256) void cast2_bf16_kernel(
    const float* __restrict__ in1, ushort* __restrict__ out1, int n1,
    const float* __restrict__ in2, ushort* __restrict__ out2, int n2) {
    int i = (blockIdx.x * 256 + threadIdx.x) * 8;
    const float* in;
    ushort* out;
    if (i < n1) {
        in = in1 + i; out = out1 + i;
    } else {
        const int j = i - n1;
        if (j + 8 > n2) return;
        in = in2 + j; out = out2 + j;
    }
    const float4v a = *(const float4v*)(in);
    const float4v b = *(const float4v*)(in + 4);
    ushort8 o;
    o[0] = f2bf(a[0]); o[1] = f2bf(a[1]); o[2] = f2bf(a[2]); o[3] = f2bf(a[3]);
    o[4] = f2bf(b[0]); o[5] = f2bf(b[1]); o[6] = f2bf(b[2]); o[7] = f2bf(b[3]);
    *(ushort8*)(out) = o;
}

// ---------------- bf16 bt-GEMM, 256x256 tile, 8-phase counted-vmcnt ----------
// (measured-best: ~144us @ 2048-K, MfmaUtil 40%, FETCH 182MB, conflicts 0.
//  BK=64, LDS 128 KiB, 1 block/CU.  BYTE-IDENTICAL to round 8.)
// EPI: 0 bf16, 1 sigmoid(acc)*Aux -> bf16, 2 f32.

#define PH_PRE() __builtin_amdgcn_s_barrier()
#define PH_POST() __builtin_amdgcn_s_barrier()

#define MFMA_Q(AF, RBASE, CL) do { \
    __builtin_amdgcn_s_setprio(1); \
    _Pragma("unroll") for (int kk = 0; kk < 2; ++kk) \
    _Pragma("unroll") for (int rm = 0; rm < 4; ++rm) \
    _Pragma("unroll") for (int cn = 0; cn < 2; ++cn) \
        acc[(RBASE) + rm][(CL) + cn] = __builtin_amdgcn_mfma_f32_16x16x32_bf16( \
            AF[rm][kk], bf[(CL) + cn][kk], acc[(RBASE) + rm][(CL) + cn], 0, 0, 0); \
    __builtin_amdgcn_s_setprio(0); } while (0)

#define READ_A(DST, BUF, HB) do { \
    _Pragma("unroll") for (int rm = 0; rm < 4; ++rm) { \
        DST[rm][0] = *(const short8*)&As[BUF][offA_k0 + ((HB) * 4 + rm) * 1024]; \
        DST[rm][1] = *(const short8*)&As[BUF][offA_k1 + ((HB) * 4 + rm) * 1024]; \
    } } while (0)

#define READ_B2(BUF, CNLO) do { \
    _Pragma("unroll") for (int cn = 0; cn < 2; ++cn) { \
        bf[(CNLO) + cn][0] = *(const short8*)&Bs[BUF][offB_k0 + ((CNLO) + cn) * 1024]; \
        bf[(CNLO) + cn][1] = *(const short8*)&Bs[BUF][offB_k1 + ((CNLO) + cn) * 1024]; \
    } } while (0)

#define STAGE(G, OFF, LBASE) do { \
    async_cp16((G) + (OFF),       (LBASE) + (tid << 3)); \
    async_cp16((G) + (OFF) + k64, (LBASE) + (tid << 3) + 4096); \
    (OFF) += 64; } while (0)

template <int EPI>
__global__ __launch_bounds__(512, 2) void gemm256(
    const ushort* __restrict__ Ab, const ushort* __restrict__ Wb,
    void* __restrict__ Out, const ushort* __restrict__ Aux,
    int M, int N, int K) {
    __shared__ ushort As[2][16384];
    __shared__ ushort Bs[2][16384];

    const int tid  = threadIdx.x;
    const int lane = tid & 63;
    const int w    = tid >> 6;
    const int wm   = w >> 2;          // 0..1
    const int wn   = w & 3;           // 0..3
    const int l15  = lane & 15;
    const int l4   = lane >> 4;       // 0..3
    const int swz7 = l15 & 7;
    const int s01  = swz7 & 3;
    const int b2   = (swz7 >> 2) & 1;

    // XCD-aware block swizzle (nwg divisible by 8 for all our shapes)
    const int gx   = gridDim.x;
    const int nwg  = gx * gridDim.y;
    const int orig = blockIdx.y * gx + blockIdx.x;
    const int swz  = (orig & 7) * (nwg >> 3) + (orig >> 3);
    const int row0 = (swz / gx) * 256;
    const int col0 = (swz % gx) * 256;

    const int ni = K >> 7;            // iterations (2 K-tiles each)

    // precomputed LDS read base offsets (elem units)
    const int commA   = (wm * 128 + l15) * 64 + (l4 ^ s01) * 8;
    const int offA_k0 = commA + (b2 ? 32 : 0);
    const int offA_k1 = commA + (b2 ? 0 : 32);
    const int commB   = (wn * 64 + l15) * 64 + (l4 ^ s01) * 8;
    const int offB_k0 = commB + (b2 ? 32 : 0);
    const int offB_k1 = commB + (b2 ? 0 : 32);

    // precomputed per-thread staging source offsets (elem units)
    const uint rr8 = (uint)(tid >> 3);
    const uint kg8 = (uint)(((tid & 7) ^ ((tid >> 3) & 7)) * 8);
    const uint k64 = (uint)64 * (uint)K;            // 64-row stride (j=1)
    uint oA0 = (uint)(row0) * (uint)K + rr8 * (uint)K + kg8;
    uint oA1 = oA0 + (uint)128 * (uint)K;
    uint oW0 = (uint)(col0) * (uint)K + rr8 * (uint)K + kg8;
    uint oW1 = oW0 + (uint)128 * (uint)K;

    float4v acc[8][4];
#pragma unroll
    for (int i2 = 0; i2 < 8; i2++)
#pragma unroll
        for (int j2 = 0; j2 < 4; j2++) {
            float4v z = {0.f, 0.f, 0.f, 0.f};
            acc[i2][j2] = z;
        }

    short8 afL[4][2], afH[4][2], bf[4][2];

    // -------- prologue: tiles 0 (buf0) and 1 (buf1); wait tile0
    STAGE(Ab, oA0, &As[0][0]);
    STAGE(Ab, oA1, &As[0][8192]);
    STAGE(Wb, oW0, &Bs[0][0]);
    STAGE(Wb, oW1, &Bs[0][8192]);
    STAGE(Ab, oA0, &As[1][0]);
    STAGE(Ab, oA1, &As[1][8192]);
    STAGE(Wb, oW0, &Bs[1][0]);
    STAGE(Wb, oW1, &Bs[1][8192]);
    asm volatile("s_waitcnt vmcnt(8)" ::: "memory");   // tile0 landed
    __builtin_amdgcn_s_barrier();

#pragma unroll 1
    for (int i = 0; i < ni - 1; ++i) {
        // ---- p1: buf0, Q(rm0-3, cn0-1); 12 ds_reads
        READ_A(afL, 0, 0);
        READ_B2(0, 0);
        asm volatile("s_waitcnt lgkmcnt(8)");
        PH_PRE();
        MFMA_Q(afL, 0, 0);
        PH_POST();

        // ---- p2: Q(rm0-3, cn2-3)
        READ_B2(0, 2);
        PH_PRE();
        MFMA_Q(afL, 0, 2);
        PH_POST();

        // ---- p3: Q(rm4-7, cn2-3); stage (u+2).Bh0
        READ_A(afH, 0, 1);
        STAGE(Wb, oW0, &Bs[0][0]);
        PH_PRE();
        MFMA_Q(afH, 4, 2);
        PH_POST();

        // ---- p4: Q(rm4-7, cn0-1); stage (u+2).Bh1; gate buf1 (tile u+1)
        STAGE(Wb, oW1, &Bs[0][8192]);
        PH_PRE();
        MFMA_Q(afH, 4, 0);
        asm volatile("s_waitcnt vmcnt(4)" ::: "memory");
        __builtin_amdgcn_s_barrier();

        // ---- p5: buf1, Q(rm0-3, cn0-1); stage (u+2).Ah0
        READ_A(afL, 1, 0);
        READ_B2(1, 0);
        STAGE(Ab, oA0, &As[0][0]);
        asm volatile("s_waitcnt lgkmcnt(8)");
        PH_PRE();
        MFMA_Q(afL, 0, 0);
        PH_POST();

        // ---- p6: Q(rm0-3, cn2-3); stage (u+2).Ah1
        READ_B2(1, 2);
        STAGE(Ab, oA1, &As[0][8192]);
        PH_PRE();
        MFMA_Q(afL, 0, 2);
        PH_POST();

        // ---- p7: Q(rm4-7, cn2-3); stage (u+3).Bh0+Bh1
        READ_A(afH, 1, 1);
        STAGE(Wb, oW0, &Bs[1][0]);
        STAGE(Wb, oW1, &Bs[1][8192]);
        PH_PRE();
        MFMA_Q(afH, 4, 2);
        PH_POST();

        // ---- p8: Q(rm4-7, cn0-1); stage (u+3).Ah0+Ah1; gate buf0 (tile u+2)
        STAGE(Ab, oA0, &As[1][0]);
        STAGE(Ab, oA1, &As[1][8192]);
        PH_PRE();
        MFMA_Q(afH, 4, 0);
        asm volatile("s_waitcnt vmcnt(8)" ::: "memory");
        __builtin_amdgcn_s_barrier();
    }

    // -------- peeled last iteration: no stages, no intra-phase barriers
    {
        READ_A(afL, 0, 0);
        READ_B2(0, 0);
        READ_B2(0, 2);
        READ_A(afH, 0, 1);
        __builtin_amdgcn_s_setprio(1);
        MFMA_Q(afL, 0, 0);
        MFMA_Q(afL, 0, 2);
        MFMA_Q(afH, 4, 2);
        MFMA_Q(afH, 4, 0);
        __builtin_amdgcn_s_setprio(0);
        asm volatile("s_waitcnt vmcnt(0)" ::: "memory");
        __builtin_amdgcn_s_barrier();
        READ_A(afL, 1, 0);
        READ_B2(1, 0);
        READ_B2(1, 2);
        READ_A(afH, 1, 1);
        __builtin_amdgcn_s_setprio(1);
        MFMA_Q(afL, 0, 0);
        MFMA_Q(afL, 0, 2);
        MFMA_Q(afH, 4, 2);
        MFMA_Q(afH, 4, 0);
        __builtin_amdgcn_s_setprio(0);
    }

    // epilogue: C/D layout col = lane&15, row = (lane>>4)*4 + reg
#pragma unroll
    for (int rm = 0; rm < 8; ++rm) {
#pragma unroll
        for (int cn = 0; cn < 4; ++cn) {
            const int r0 = row0 + wm * 128 + rm * 16 + l4 * 4;
            const int cc = col0 + wn * 64 + cn * 16 + l15;
#pragma unroll
            for (int rr = 0; rr < 4; ++rr) {
                const float v = acc[rm][cn][rr];
                const size_t off = (size_t)(r0 + rr) * N + cc;
                if (EPI == 0) {
                    ((ushort*)Out)[off] = f2bf(v);
                } else if (EPI == 1) {
                    const float g = 1.0f / (1.0f + __expf(-v));
                    ((ushort*)Out)[off] = f2bf(g * bf2f(Aux[off]));
                } else {
                    ((float*)Out)[off] = v;
                }
            }
        }
    }
}

// ---------------- fused conv+silu+dt+scan kernels (X never materialized) ----
// Geometry (both A and B): 512 scan blocks x 128 threads; block = (batch b,
// chunk chk, slice) with slice covering 512 channels; lane owns 4 channels
// (us4 8B loads).  Head = 64 ch = 16 lanes -> dt reduce = in-lane sum of
// 4 + shfl_xor(1,2,4,8).  conv recomputed identically in A and B (bit-equal
// f32 path) so A's chunk aggregates compose exactly with B's rescan.

__device__ __forceinline__ void conv_row_setup(
    const float* __restrict__ cw, const float* __restrict__ cb,
    const float* __restrict__ dtw, int c0,
    float4v w[4], float4v* bias, float4v* dtwv) {
    const float4v* wp = (const float4v*)(cw + (size_t)c0 * 4);
#pragma unroll
    for (int j = 0; j < 4; ++j) w[j] = wp[j];     // w[j] = taps of channel c0+j
    *bias = *(const float4v*)(cb + c0);
    *dtwv = *(const float4v*)(dtw + c0);
}

// computes sl[4] (silu outputs) and dtv for one row; shifts window
__device__ __forceinline__ float conv_row(
    const us4 cur, float4v* f0, float4v* f1, float4v* f2,
    const float4v w[4], const float4v bias, const float4v dtwv,
    const float dtbv, float sl[4]) {
    float4v fc;
#pragma unroll
    for (int j = 0; j < 4; ++j) fc[j] = bf2f(cur[j]);
    float d = 0.0f;
#pragma unroll
    for (int j = 0; j < 4; ++j) {
        const float a4 = bias[j] + w[j][0] * (*f0)[j] + w[j][1] * (*f1)[j]
                       + w[j][2] * (*f2)[j] + w[j][3] * fc[j];
        const float s = a4 / (1.0f + __expf(-a4));
        sl[j] = s;
        d += s * dtwv[j];
    }
    *f0 = *f1; *f1 = *f2; *f2 = fc;
    d += __shfl_xor(d, 1, 64);
    d += __shfl_xor(d, 2, 64);
    d += __shfl_xor(d, 4, 64);
    d += __shfl_xor(d, 8, 64);
    const float z = d + dtbv;
    return (z > 20.0f) ? z : __logf(1.0f + __expf(z));
}

// Kernel A: chunk-local scan aggregates -> sumP/sumS.  Grid-fused castGate:
// blocks >= NSCAN cast w_gate f32->bf16 (exact fit: 8192 blocks * 1024).
__global__ __launch_bounds__(128) void conv_scanA(
    const ushort* __restrict__ proj, const float* __restrict__ cw,
    const float* __restrict__ cb, const float* __restrict__ dtw,
    const float* __restrict__ dtb, const float* __restrict__ A_log,
    const float* __restrict__ Bv, float* __restrict__ sumP,
    float* __restrict__ sumS,
    const float* __restrict__ wg, ushort* __restrict__ wgb) {
    const int bid = blockIdx.x;
    if (bid >= NSCAN) {   // castGate part
        const int i = (bid - NSCAN) * 1024 + threadIdx.x * 8;
        const float4v a = *(const float4v*)(wg + i);
        const float4v b = *(const float4v*)(wg + i + 4);
        ushort8 o;
        o[0] = f2bf(a[0]); o[1] = f2bf(a[1]); o[2] = f2bf(a[2]); o[3] = f2bf(a[3]);
        o[4] = f2bf(b[0]); o[5] = f2bf(b[1]); o[6] = f2bf(b[2]); o[7] = f2bf(b[3]);
        *(ushort8*)(wgb + i) = o;
        return;
    }
    const int slice = bid & 7;
    const int chk   = (bid >> 3) & 31;
    const int b     = bid >> 8;
    const int tid   = threadIdx.x;
    const int c0    = slice * 512 + tid * 4;
    const int h     = c0 >> 6;
    const int bl0   = b * LSEQ + chk * CHLEN;

    float4v w[4], bias, dtwv;
    conv_row_setup(cw, cb, dtw, c0, w, &bias, &dtwv);
    const float dtbv = dtb[h];
    const float4v Alv = *(const float4v*)(A_log + c0);
    const float4v Bc  = *(const float4v*)(Bv + c0);
    float Ac[4];
#pragma unroll
    for (int j = 0; j < 4; ++j) Ac[j] = -__expf(Alv[j]);

    const size_t base = (size_t)bl0 * INNERC + c0;
    float4v f0, f1, f2;
    if (chk == 0) {
#pragma unroll
        for (int j = 0; j < 4; ++j) { f0[j] = 0.f; f1[j] = 0.f; f2[j] = 0.f; }
    } else {
        const us4 u0 = *(const us4*)(proj + base - 3 * (size_t)INNERC);
        const us4 u1 = *(const us4*)(proj + base - 2 * (size_t)INNERC);
        const us4 u2 = *(const us4*)(proj + base - 1 * (size_t)INNERC);
#pragma unroll
        for (int j = 0; j < 4; ++j) {
            f0[j] = bf2f(u0[j]); f1[j] = bf2f(u1[j]); f2[j] = bf2f(u2[j]);
        }
    }

    float4v Pr, sv;
#pragma unroll
    for (int j = 0; j < 4; ++j) { Pr[j] = 1.0f; sv[j] = 0.0f; }
#pragma unroll 4
    for (int r = 0; r < CHLEN; ++r) {
        const us4 cur = *(const us4*)(proj + base + (size_t)r * INNERC);
        float sl[4];
        const float dtv = conv_row(cur, &f0, &f1, &f2, w, bias, dtwv, dtbv, sl);
#pragma unroll
        for (int j = 0; j < 4; ++j) {
            const float aa = __expf(dtv * Ac[j]);
            Pr[j] *= aa;
            sv[j] = aa * sv[j] + dtv * Bc[j] * sl[j];
        }
    }
    const size_t task = (size_t)((b * 64 + h) * 32 + chk);
    const int p4 = (tid & 15) * 4;
    *(float4v*)(sumP + task * 64 + p4) = Pr;
    *(float4v*)(sumS + task * 64 + p4) = sv;
}

// Kernel B: inline carry from sums, full rescan, write y -> Y (bf16, d_out).
__global__ __launch_bounds__(128) void conv_scanB(
    const ushort* __restrict__ proj, const float* __restrict__ cw,
    const float* __restrict__ cb, const float* __restrict__ dtw,
    const float* __restrict__ dtb, const float* __restrict__ A_log,
    const float* __restrict__ Bv, const float* __restrict__ Cv,
    const float* __restrict__ Dv, const float* __restrict__ sumP,
    const float* __restrict__ sumS, ushort* __restrict__ Y) {
    const int bid   = blockIdx.x;
    const int slice = bid & 7;
    const int chk   = (bid >> 3) & 31;
    const int b     = bid >> 8;
    const int tid   = threadIdx.x;
    const int c0    = slice * 512 + tid * 4;
    const int h     = c0 >> 6;
    const int bl0   = b * LSEQ + chk * CHLEN;

    float4v w[4], bias, dtwv;
    conv_row_setup(cw, cb, dtw, c0, w, &bias, &dtwv);
    const float dtbv = dtb[h];
    const float4v Alv = *(const float4v*)(A_log + c0);
    const float4v Bc  = *(const float4v*)(Bv + c0);
    const float4v Cc  = *(const float4v*)(Cv + c0);
    const float4v Dc  = *(const float4v*)(Dv + c0);
    float Ac[4];
#pragma unroll
    for (int j = 0; j < 4; ++j) Ac[j] = -__expf(Alv[j]);

    // carry over earlier chunks of this (b,h) from L2-resident sums
    const int p4 = (tid & 15) * 4;
    const size_t bh32 = (size_t)(b * 64 + h) * 32;
    float4v sv;
#pragma unroll
    for (int j = 0; j < 4; ++j) sv[j] = 0.0f;
    for (int jc = 0; jc < chk; ++jc) {
        const float4v P = *(const float4v*)(sumP + (bh32 + jc) * 64 + p4);
        const float4v S = *(const float4v*)(sumS + (bh32 + jc) * 64 + p4);
#pragma unroll
        for (int j = 0; j < 4; ++j) sv[j] = P[j] * sv[j] + S[j];
    }

    const size_t base = (size_t)bl0 * INNERC + c0;
    float4v f0, f1, f2;
    if (chk == 0) {
#pragma unroll
        for (int j = 0; j < 4; ++j) { f0[j] = 0.f; f1[j] = 0.f; f2[j] = 0.f; }
    } else {
        const us4 u0 = *(const us4*)(proj + base - 3 * (size_t)INNERC);
        const us4 u1 = *(const us4*)(proj + base - 2 * (size_t)INNERC);
        const us4 u2 = *(const us4*)(proj + base - 1 * (size_t)INNERC);
#pragma unroll
        for (int j = 0; j < 4; ++j) {
            f0[j] = bf2f(u0[j]); f1[j] = bf2f(u1[j]); f2[j] = bf2f(u2[j]);
        }
    }

#pragma unroll 4
    for (int r = 0; r < CHLEN; ++r) {
        const us4 cur = *(const us4*)(proj + base + (size_t)r * INNERC);
        float sl[4];
        const float dtv = conv_row(cur, &f0, &f1, &f2, w, bias, dtwv, dtbv, sl);
        us4 yo;
#pragma unroll
        for (int j = 0; j < 4; ++j) {
            const float aa = __expf(dtv * Ac[j]);
            sv[j] = aa * sv[j] + dtv * Bc[j] * sl[j];
            yo[j] = f2bf(Cc[j] * sv[j] + Dc[j] * sl[j]);
        }
        *(us4*)(Y + base + (size_t)r * INNERC) = yo;
    }
}

// ---------------- workspace layout (bytes) ----------------
#define OFF_PROJ  ((size_t)0)            // 67,108,864 : proj -> comb
#define OFF_HID   ((size_t)67108864)     // 33,554,432 : hidden bf16
#define OFF_WB    ((size_t)100663296)    // 16,777,216 : weight bf16 (reused 3x)
#define OFF_DT    ((size_t)117440512)    //  2,097,152 (unused; layout kept)
#define OFF_SUMP  ((size_t)119537664)    //  1,048,576
#define OFF_SUMS  ((size_t)120586240)    //  1,048,576
#define OFF_CARRY ((size_t)121634816)    //  1,048,576 (unused; layout kept)
#define WS_NEEDED ((size_t)122683392)    // = 117 MiB

extern "C" void kernel_launch(void* const* d_in, const int* in_sizes, int n_in,
                              void* d_out, int out_size, void* d_ws, size_t ws_size,
                              hipStream_t stream) {
    if (ws_size < WS_NEEDED) {
        diag_kernel<<<1, 64, 0, stream>>>((float*)d_out, (float)(ws_size >> 20));
        return;
    }
    const float* hidden = (const float*)d_in[0];
    const float* w_in   = (const float*)d_in[1];
    const float* w_gate = (const float*)d_in[2];
    const float* w_out  = (const float*)d_in[3];
    const float* conv_w = (const float*)d_in[4];
    const float* conv_b = (const float*)d_in[5];
    const float* dt_w   = (const float*)d_in[6];
    const float* dt_b   = (const float*)d_in[7];
    const float* A_log  = (const float*)d_in[8];
    const float* Bv     = (const float*)d_in[9];
    const float* Cv     = (const float*)d_in[10];
    const float* Dv     = (const float*)d_in[11];

    char* ws = (char*)d_ws;
    ushort* projbuf = (ushort*)(ws + OFF_PROJ);   // proj, then comb
    ushort* hid16   = (ushort*)(ws + OFF_HID);
    ushort* wbuf    = (ushort*)(ws + OFF_WB);
    float*  sumP    = (float*)(ws + OFF_SUMP);
    float*  sumS    = (float*)(ws + OFF_SUMS);
    ushort* y16     = (ushort*)d_out;             // Y scratch inside d_out

    // hidden + in_proj weight casts in one launch
    cast2_bf16_kernel<<<12288, 256, 0, stream>>>(
        hidden, hid16, MROWS * DM, w_in, wbuf, INNERC * DM);

    // in_proj GEMM -> proj (bf16)
    gemm256<0><<<dim3(INNERC / 256, MROWS / 256), 512, 0, stream>>>(
        hid16, wbuf, projbuf, nullptr, MROWS, INNERC, DM);

    // A: conv+silu+dt+chunk-scan aggregates (X never materialized);
    //    grid-fused castGate (w_gate -> wbuf, free after in GEMM)
    conv_scanA<<<NSCAN + 8192, 128, 0, stream>>>(
        projbuf, conv_w, conv_b, dt_w, dt_b, A_log, Bv, sumP, sumS,
        w_gate, wbuf);

    // B: inline carry + rescan, write Y (bf16) into d_out
    conv_scanB<<<NSCAN, 128, 0, stream>>>(
        projbuf, conv_w, conv_b, dt_w, dt_b, A_log, Bv, Cv, Dv,
        sumP, sumS, y16);

    // gate GEMM with fused gating: comb = sigmoid(G) * Y -> projbuf
    gemm256<1><<<dim3(INNERC / 256, MROWS / 256), 512, 0, stream>>>(
        hid16, wbuf, projbuf, y16, MROWS, INNERC, DM);

    // output projection (f32 out) — overwrites Y scratch in d_out
    cast_bf16_kernel<<<4096, 256, 0, stream>>>(w_out, wbuf, DM * INNERC);
    gemm256<2><<<dim3(DM / 256, MROWS / 256), 512, 0, stream>>>(
        projbuf, wbuf, d_out, nullptr, MROWS, DM, INNERC);
}